// Round 7
// baseline (346.263 us; speedup 1.0000x reference)
//
#include <hip/hip_runtime.h>

#define IMG 512
#define NB 8            // 16-row bands per block (128 rows/block)
#define RS 32           // ring slots (power of 2; 26 live + 16 stores w/ WAR barrier)

// Gaussian window, sigma=1.5, ws=11, normalized (matches reference _make_window)
#define W0f 1.0283800e-03f
#define W1f 7.5987582e-03f
#define W2f 3.6000773e-02f
#define W3f 1.0936070e-01f
#define W4f 2.1300553e-01f
#define W5f 2.6601172e-01f

typedef _Float16 h1;
typedef h1 h2 __attribute__((ext_vector_type(2)));
typedef float f2 __attribute__((ext_vector_type(2)));

__device__ __forceinline__ f2 pkfma(f2 a, f2 b, f2 c) {
    return __builtin_elementwise_fma(a, b, c);
}

// Raw workgroup barrier: drain LDS only, leave global loads in flight.
#define LGKM_BARRIER() asm volatile("s_waitcnt lgkmcnt(0)\n\ts_barrier" ::: "memory")

// 16 KB ring + 8 blocks/CU = 32 waves/CU (HW max). Stall-bound at low
// occupancy was the R4/R6 wall (both 77us with very different VALU streams).
__global__ __launch_bounds__(256, 8)
void ssim_main(const float* __restrict__ img1, const float* __restrict__ img2,
               float* __restrict__ part)
{
    // Ring: 32 slots x 64 px x 8 B = 16 KB. Px = (x,y,s,p) as 4 f16
    // (s = x^2+y^2, p = x*y after h-blur). slot(gr) = gr & 31.
    // ALL arithmetic f32 (f16 accumulation bias ~2e-5 in sigma12 x45 gain
    // -> 1e-3 final error, measured R5). Only STORAGE is f16 (RN, unbiased;
    // validated R6: absmax 0.0).
    __shared__ float4 ringRaw[RS * 32];
    float2* const rp2 = (float2*)ringRaw;

    const float Wt[11] = {W0f,W1f,W2f,W3f,W4f,W5f,W4f,W3f,W2f,W1f,W0f};
    constexpr float C1 = 1.0e-4f, C2 = 9.0e-4f;

    const int bx     = blockIdx.x;
    const int n      = bx >> 5;            // image 0..63
    const int stripe = (bx >> 2) & 7;      // 64-col stripe
    const int q      = bx & 3;             // row quarter
    const int gx0    = stripe << 6;
    const int base   = q << 7;
    const int tid    = threadIdx.x;
    const bool edge  = (stripe == 0) | (stripe == 7);

    const float* __restrict__ b1p = img1 + (size_t)n * IMG * IMG;
    const float* __restrict__ b2p = img2 + (size_t)n * IMG * IMG;

    float acc = 0.f;

    // ---- load 20-col window (5 aligned float4 per image), predicated
    auto loadRow = [&](int gr, int gcb, float4* PX, float4* PY) {
        const float* r1 = b1p + (ptrdiff_t)gr * IMG + (gcb - 8);
        const float* r2 = b2p + (ptrdiff_t)gr * IMG + (gcb - 8);
        const bool rok = (unsigned)gr < (unsigned)IMG;
        if (rok & (!edge)) {
            #pragma unroll
            for (int t = 0; t < 5; ++t) {
                PX[t] = ((const float4*)r1)[t];
                PY[t] = ((const float4*)r2)[t];
            }
        } else {
            #pragma unroll
            for (int t = 0; t < 5; ++t) {
                int gc = gcb - 8 + (t << 2);
                bool ok = rok && (gc >= 0) && (gc <= IMG - 4);
                PX[t] = ok ? ((const float4*)r1)[t] : make_float4(0.f,0.f,0.f,0.f);
                PY[t] = ok ? ((const float4*)r2)[t] : make_float4(0.f,0.f,0.f,0.f);
            }
        }
    };

    // ---- h-blur (f32) of preloaded row -> f16 ring row, 4 cols (cg*4..+3)
    auto horizStore = [&](int gr, int cg, const float4* PX, const float4* PY) {
        float X[20], Y[20];
        #pragma unroll
        for (int t = 0; t < 5; ++t) {
            X[4*t]=PX[t].x; X[4*t+1]=PX[t].y; X[4*t+2]=PX[t].z; X[4*t+3]=PX[t].w;
            Y[4*t]=PY[t].x; Y[4*t+1]=PY[t].y; Y[4*t+2]=PY[t].z; Y[4*t+3]=PY[t].w;
        }
        f2 pxy[14], psp[14];
        #pragma unroll
        for (int j = 0; j < 14; ++j) {
            float x = X[3+j], y = Y[3+j];
            pxy[j] = f2{x, y};
            psp[j] = f2{fmaf(x, x, y*y), x*y};
        }
        f2 axy[4], asp[4];
        #pragma unroll
        for (int o = 0; o < 4; ++o) {
            f2 m = {0.f,0.f}, t2 = {0.f,0.f};
            #pragma unroll
            for (int k = 0; k < 11; ++k) {
                f2 w2 = {Wt[k], Wt[k]};
                m  = pkfma(w2, pxy[o+k], m);
                t2 = pkfma(w2, psp[o+k], t2);
            }
            axy[o] = m; asp[o] = t2;
        }
        // pack: px = (h16 x, h16 y, h16 s, h16 p) -- RN casts (bias-free)
        const int slot = (gr + 64) & (RS - 1);
        float4* dst = ringRaw + (slot << 5) + (cg << 1);
        #pragma unroll
        for (int pp = 0; pp < 2; ++pp) {
            float4 st;
            h2 a0 = h2{(h1)axy[2*pp].x,   (h1)axy[2*pp].y};
            h2 b0 = h2{(h1)asp[2*pp].x,   (h1)asp[2*pp].y};
            h2 a1 = h2{(h1)axy[2*pp+1].x, (h1)axy[2*pp+1].y};
            h2 b1 = h2{(h1)asp[2*pp+1].x, (h1)asp[2*pp+1].y};
            st.x = __builtin_bit_cast(float, a0);
            st.y = __builtin_bit_cast(float, b0);
            st.z = __builtin_bit_cast(float, a1);
            st.w = __builtin_bit_cast(float, b1);
            dst[pp] = st;
        }
    };

    // ---- vert blur + SSIM: 4 rows/thread, f16 loads, f32 accumulation (mix)
    auto vert = [&](int b) {
        const int wv  = __builtin_amdgcn_readfirstlane(tid >> 6);
        const int col = tid & 63;
        const int gr0 = base + (b << 4) + (wv << 2) - 5 + 64;   // >= 0
        h2 vxy[14], vsp[14];
        #pragma unroll
        for (int i = 0; i < 14; ++i) {
            const int slot = (gr0 + i) & (RS - 1);              // scalar
            float2 qv = rp2[(slot << 6) + col];                 // ds_read_b64
            vxy[i] = __builtin_bit_cast(h2, qv.x);
            vsp[i] = __builtin_bit_cast(h2, qv.y);
        }
        #pragma unroll
        for (int qd = 0; qd < 4; ++qd) {
            float m1=0.f, m2=0.f, ts=0.f, tp=0.f;
            #pragma unroll
            for (int k = 0; k < 11; ++k) {
                const float w = Wt[k];
                m1 = fmaf((float)vxy[qd+k].x, w, m1);   // v_fma_mix_f32
                m2 = fmaf((float)vxy[qd+k].y, w, m2);
                ts = fmaf((float)vsp[qd+k].x, w, ts);
                tp = fmaf((float)vsp[qd+k].y, w, tp);
            }
            float mu12  = m1 * m2;
            float musum = fmaf(m1, m1, m2*m2);
            float g12 = tp - mu12;                      // sigma12
            float gs  = ts - musum;                     // sigma1^2+sigma2^2
            float num = fmaf(2.f, mu12, C1) * fmaf(2.f, g12, C2);
            float den = (musum + C1) * (gs + C2);
            acc = fmaf(num, __builtin_amdgcn_rcpf(den), acc);
        }
    };

    const int ri  = tid >> 4;              // staging row 0..15
    const int cg  = tid & 15;              // staging col-group (4 cols)
    const int gcb = gx0 + (cg << 2);

    // ---- prologue: stage rows base-5 .. base+20 (26 rows x 16 col-groups)
    {
        float4 PX[5], PY[5];
        int gr = base - 5 + ri;
        loadRow(gr, gcb, PX, PY);
        horizStore(gr, cg, PX, PY);
        int task = tid + 256;              // rows 16..25
        if (task < 26 * 16) {
            int gr2 = base - 5 + (task >> 4);
            int cg2 = task & 15;
            loadRow(gr2, gx0 + (cg2 << 2), PX, PY);
            horizStore(gr2, cg2, PX, PY);
        }
    }

    // ---- initial prefetch: rows base+21..base+36 (stored after vert(0))
    float4 PX[5], PY[5];
    loadRow(base + 21 + ri, gcb, PX, PY);

    // ---- main loop: 2 barriers/band (RS=32 < 26+16 live span needs WAR).
    // 8 independent blocks/CU cross-hide the per-band load/barrier stalls.
    for (int b = 0; b < NB; ++b) {
        const int r0 = base + (b << 4);
        LGKM_BARRIER();                    // RAW: stores from band b-1 visible
        vert(b);
        LGKM_BARRIER();                    // WAR: vert reads of band b done
        if (b < NB-1) {
            horizStore(r0 + 21 + ri, cg, PX, PY);
            if (b < NB-2) loadRow(r0 + 37 + ri, gcb, PX, PY);
        }
    }

    // ---- block reduction (reuse ring LDS after final barrier)
    #pragma unroll
    for (int off = 32; off > 0; off >>= 1)
        acc += __shfl_down(acc, off, 64);
    LGKM_BARRIER();                        // last vert reads complete
    if ((tid & 63) == 0) ((float*)ringRaw)[tid >> 6] = acc;
    LGKM_BARRIER();
    if (tid == 0) {
        const float* r = (const float*)ringRaw;
        part[bx] = r[0] + r[1] + r[2] + r[3];
    }
}

__global__ void ssim_finalize(const float* __restrict__ part, float* __restrict__ out)
{
    double s = 0.0;
    const int t = threadIdx.x;
    for (int i = t; i < 2048; i += 64) s += (double)part[i];
    #pragma unroll
    for (int off = 32; off > 0; off >>= 1)
        s += __shfl_down(s, off, 64);
    if (t == 0) out[0] = (float)(s * (1.0 / 16777216.0));
}

extern "C" void kernel_launch(void* const* d_in, const int* in_sizes, int n_in,
                              void* d_out, int out_size, void* d_ws, size_t ws_size,
                              hipStream_t stream)
{
    const float* img1 = (const float*)d_in[0];
    const float* img2 = (const float*)d_in[1];
    float* out  = (float*)d_out;
    float* part = (float*)d_ws;      // 2048 floats of scratch

    ssim_main<<<2048, 256, 0, stream>>>(img1, img2, part);
    ssim_finalize<<<1, 64, 0, stream>>>(part, out);
}

// Round 8
// 185.499 us; speedup vs baseline: 1.8667x; 1.8667x over previous
//
#include <hip/hip_runtime.h>

#define IMG 512
#define NB 8            // 16-row bands per block (128 rows/block)
#define RS 32           // ring slots (16 KB); 2 barriers/band (WAR needed)

// Gaussian window, sigma=1.5, ws=11, normalized (matches reference _make_window)
#define W0f 1.0283800e-03f
#define W1f 7.5987582e-03f
#define W2f 3.6000773e-02f
#define W3f 1.0936070e-01f
#define W4f 2.1300553e-01f
#define W5f 2.6601172e-01f

typedef _Float16 h1;
typedef h1 h2 __attribute__((ext_vector_type(2)));
typedef float f2 __attribute__((ext_vector_type(2)));
typedef float f4 __attribute__((ext_vector_type(4)));

__device__ __forceinline__ f2 pkfma(f2 a, f2 b, f2 c) {
    return __builtin_elementwise_fma(a, b, c);
}

// Raw workgroup barrier: drain LDS only, leave global loads in flight.
#define LGKM_BARRIER() asm volatile("s_waitcnt lgkmcnt(0)\n\ts_barrier" ::: "memory")

// Explicit 5x16B row-window load, pinned in program order (volatile asm).
// Results are NOT tracked by the compiler's waitcnt insertion — consumption
// must go through VMWAIT10 below. "=&v": early-clobber so outputs never
// alias the address pair while loads are in flight.
#define GL5(d0,d1,d2,d3,d4,p)                                         \
  asm volatile("global_load_dwordx4 %0, %5, off\n\t"                  \
               "global_load_dwordx4 %1, %5, off offset:16\n\t"        \
               "global_load_dwordx4 %2, %5, off offset:32\n\t"        \
               "global_load_dwordx4 %3, %5, off offset:48\n\t"        \
               "global_load_dwordx4 %4, %5, off offset:64"            \
               : "=&v"(d0),"=&v"(d1),"=&v"(d2),"=&v"(d3),"=&v"(d4)    \
               : "v"(p) : "memory")

// Wait for the async loads; ties all 10 result vectors as dataflow operands
// so no consumer arithmetic can be scheduled above the wait.
#define VMWAIT10(a0,a1,a2,a3,a4,b0,b1,b2,b3,b4)                       \
  asm volatile("s_waitcnt vmcnt(0)"                                   \
               : "+v"(a0),"+v"(a1),"+v"(a2),"+v"(a3),"+v"(a4),        \
                 "+v"(b0),"+v"(b1),"+v"(b2),"+v"(b3),"+v"(b4))

__global__ __launch_bounds__(256, 4)
void ssim_main(const float* __restrict__ img1, const float* __restrict__ img2,
               float* __restrict__ part)
{
    // Ring: 32 slots x 64 px x 8 B = 16 KB. Px = (x,y,s,p) as 4 f16
    // (s = x^2+y^2, p = x*y after h-blur). slot(gr) = (gr+64) & 31.
    // ALL arithmetic f32 (f16 accumulation bias ~2e-5 in sigma12, x45 gain ->
    // 1e-3 final error, measured R5). Only STORAGE is f16 (RN, unbiased;
    // validated R6: absmax 0.0).
    __shared__ f4 ringRaw[RS * 32];
    float2* const rp2 = (float2*)ringRaw;

    const float Wt[11] = {W0f,W1f,W2f,W3f,W4f,W5f,W4f,W3f,W2f,W1f,W0f};
    constexpr float C1 = 1.0e-4f, C2 = 9.0e-4f;

    const int bx     = blockIdx.x;
    const int n      = bx >> 5;            // image 0..63
    const int stripe = (bx >> 2) & 7;      // 64-col stripe
    const int q      = bx & 3;             // row quarter
    const int gx0    = stripe << 6;
    const int base   = q << 7;
    const int tid    = threadIdx.x;
    const bool edge  = (stripe == 0) | (stripe == 7);

    const float* __restrict__ b1p = img1 + (size_t)n * IMG * IMG;
    const float* __restrict__ b2p = img2 + (size_t)n * IMG * IMG;

    float acc = 0.f;

    // ---- compiler-managed predicated load (prologue / edge / row-unsafe)
    auto loadRow = [&](int gr, int gcb, f4* PX, f4* PY) {
        const float* r1 = b1p + (ptrdiff_t)gr * IMG + (gcb - 8);
        const float* r2 = b2p + (ptrdiff_t)gr * IMG + (gcb - 8);
        const bool rok = (unsigned)gr < (unsigned)IMG;
        if (rok & (!edge)) {
            #pragma unroll
            for (int t = 0; t < 5; ++t) {
                PX[t] = ((const f4*)r1)[t];
                PY[t] = ((const f4*)r2)[t];
            }
        } else {
            #pragma unroll
            for (int t = 0; t < 5; ++t) {
                int gc = gcb - 8 + (t << 2);
                bool ok = rok && (gc >= 0) && (gc <= IMG - 4);
                PX[t] = ok ? ((const f4*)r1)[t] : (f4)0.f;
                PY[t] = ok ? ((const f4*)r2)[t] : (f4)0.f;
            }
        }
    };

    // ---- h-blur (f32) of preloaded row -> f16 ring row, 4 cols (cg*4..+3)
    auto horizStore = [&](int gr, int cg, const f4* PX, const f4* PY) {
        float X[20], Y[20];
        #pragma unroll
        for (int t = 0; t < 5; ++t) {
            X[4*t]=PX[t].x; X[4*t+1]=PX[t].y; X[4*t+2]=PX[t].z; X[4*t+3]=PX[t].w;
            Y[4*t]=PY[t].x; Y[4*t+1]=PY[t].y; Y[4*t+2]=PY[t].z; Y[4*t+3]=PY[t].w;
        }
        f2 pxy[14], psp[14];
        #pragma unroll
        for (int j = 0; j < 14; ++j) {
            float x = X[3+j], y = Y[3+j];
            pxy[j] = f2{x, y};
            psp[j] = f2{fmaf(x, x, y*y), x*y};
        }
        f2 axy[4], asp[4];
        #pragma unroll
        for (int o = 0; o < 4; ++o) {
            f2 m = {0.f,0.f}, t2 = {0.f,0.f};
            #pragma unroll
            for (int k = 0; k < 11; ++k) {
                f2 w2 = {Wt[k], Wt[k]};
                m  = pkfma(w2, pxy[o+k], m);
                t2 = pkfma(w2, psp[o+k], t2);
            }
            axy[o] = m; asp[o] = t2;
        }
        const int slot = (gr + 64) & (RS - 1);
        f4* dst = ringRaw + (slot << 5) + (cg << 1);
        #pragma unroll
        for (int pp = 0; pp < 2; ++pp) {
            f4 st;
            h2 a0 = h2{(h1)axy[2*pp].x,   (h1)axy[2*pp].y};
            h2 b0 = h2{(h1)asp[2*pp].x,   (h1)asp[2*pp].y};
            h2 a1 = h2{(h1)axy[2*pp+1].x, (h1)axy[2*pp+1].y};
            h2 b1 = h2{(h1)asp[2*pp+1].x, (h1)asp[2*pp+1].y};
            st.x = __builtin_bit_cast(float, a0);
            st.y = __builtin_bit_cast(float, b0);
            st.z = __builtin_bit_cast(float, a1);
            st.w = __builtin_bit_cast(float, b1);
            dst[pp] = st;
        }
    };

    // ---- vert blur + SSIM: 4 rows/thread, f16 loads, f32 accumulation (mix)
    auto vert = [&](int b) {
        const int wv  = __builtin_amdgcn_readfirstlane(tid >> 6);
        const int col = tid & 63;
        const int gr0 = base + (b << 4) + (wv << 2) - 5 + 64;   // >= 0
        h2 vxy[14], vsp[14];
        #pragma unroll
        for (int i = 0; i < 14; ++i) {
            const int slot = (gr0 + i) & (RS - 1);              // scalar
            float2 qv = rp2[(slot << 6) + col];                 // ds_read_b64
            vxy[i] = __builtin_bit_cast(h2, qv.x);
            vsp[i] = __builtin_bit_cast(h2, qv.y);
        }
        #pragma unroll
        for (int qd = 0; qd < 4; ++qd) {
            float m1=0.f, m2=0.f, ts=0.f, tp=0.f;
            #pragma unroll
            for (int k = 0; k < 11; ++k) {
                const float w = Wt[k];
                m1 = fmaf((float)vxy[qd+k].x, w, m1);   // v_fma_mix_f32
                m2 = fmaf((float)vxy[qd+k].y, w, m2);
                ts = fmaf((float)vsp[qd+k].x, w, ts);
                tp = fmaf((float)vsp[qd+k].y, w, tp);
            }
            float mu12  = m1 * m2;
            float musum = fmaf(m1, m1, m2*m2);
            float g12 = tp - mu12;                      // sigma12
            float gs  = ts - musum;                     // sigma1^2+sigma2^2
            float num = fmaf(2.f, mu12, C1) * fmaf(2.f, g12, C2);
            float den = (musum + C1) * (gs + C2);
            acc = fmaf(num, __builtin_amdgcn_rcpf(den), acc);
        }
    };

    const int ri  = tid >> 4;              // staging row 0..15
    const int cg  = tid & 15;              // staging col-group (4 cols)
    const int gcb = gx0 + (cg << 2);

    // ---- prologue: stage rows base-5 .. base+20 (26 rows x 16 col-groups)
    {
        f4 PX[5], PY[5];
        int gr = base - 5 + ri;
        loadRow(gr, gcb, PX, PY);
        horizStore(gr, cg, PX, PY);
        int task = tid + 256;              // rows 16..25
        if (task < 26 * 16) {
            int gr2 = base - 5 + (task >> 4);
            int cg2 = task & 15;
            loadRow(gr2, gx0 + (cg2 << 2), PX, PY);
            horizStore(gr2, cg2, PX, PY);
        }
    }

    // ---- initial prefetch: rows base+21..base+36 (consumed by b=0 store)
    f4 PX[5], PY[5];
    const float* ap1 = b1p + (ptrdiff_t)(base + 21 + ri) * IMG + (gcb - 8);
    const float* ap2 = b2p + (ptrdiff_t)(base + 21 + ri) * IMG + (gcb - 8);
    if (!edge) {
        GL5(PX[0],PX[1],PX[2],PX[3],PX[4], ap1);
        GL5(PY[0],PY[1],PY[2],PY[3],PY[4], ap2);
    } else {
        loadRow(base + 21 + ri, gcb, PX, PY);
    }
    ap1 += 16 * IMG;  ap2 += 16 * IMG;     // now at rows base+37+ri

    // ---- main loop: 2 barriers/band; async loads stay in flight across
    // vert + both barriers (consumed one full band after issue).
    for (int b = 0; b < NB; ++b) {
        const int r0 = base + (b << 4);
        LGKM_BARRIER();                    // RAW: stores of band b-1 visible
        vert(b);
        LGKM_BARRIER();                    // WAR: vert reads of band b done
        if (b < NB-1) {
            VMWAIT10(PX[0],PX[1],PX[2],PX[3],PX[4],
                     PY[0],PY[1],PY[2],PY[3],PY[4]);
            horizStore(r0 + 21 + ri, cg, PX, PY);
            if (b < NB-2) {
                // rows r0+37..r0+52; async unless edge or (q==3 && b==5,
                // where rows 501..516 need per-lane row predication)
                const bool asyn = (!edge) && !((q == 3) & (b == 5));
                if (asyn) {
                    GL5(PX[0],PX[1],PX[2],PX[3],PX[4], ap1);
                    GL5(PY[0],PY[1],PY[2],PY[3],PY[4], ap2);
                } else {
                    loadRow(r0 + 37 + ri, gcb, PX, PY);
                }
                ap1 += 16 * IMG;  ap2 += 16 * IMG;
            }
        }
    }

    // ---- block reduction (reuse ring LDS after final barrier)
    #pragma unroll
    for (int off = 32; off > 0; off >>= 1)
        acc += __shfl_down(acc, off, 64);
    LGKM_BARRIER();                        // last vert reads complete
    if ((tid & 63) == 0) ((float*)ringRaw)[tid >> 6] = acc;
    LGKM_BARRIER();
    if (tid == 0) {
        const float* r = (const float*)ringRaw;
        part[bx] = r[0] + r[1] + r[2] + r[3];
    }
}

__global__ void ssim_finalize(const float* __restrict__ part, float* __restrict__ out)
{
    double s = 0.0;
    const int t = threadIdx.x;
    for (int i = t; i < 2048; i += 64) s += (double)part[i];
    #pragma unroll
    for (int off = 32; off > 0; off >>= 1)
        s += __shfl_down(s, off, 64);
    if (t == 0) out[0] = (float)(s * (1.0 / 16777216.0));
}

extern "C" void kernel_launch(void* const* d_in, const int* in_sizes, int n_in,
                              void* d_out, int out_size, void* d_ws, size_t ws_size,
                              hipStream_t stream)
{
    const float* img1 = (const float*)d_in[0];
    const float* img2 = (const float*)d_in[1];
    float* out  = (float*)d_out;
    float* part = (float*)d_ws;      // 2048 floats of scratch

    ssim_main<<<2048, 256, 0, stream>>>(img1, img2, part);
    ssim_finalize<<<1, 64, 0, stream>>>(part, out);
}